// Round 1
// baseline (1706.957 us; speedup 1.0000x reference)
//
#include <hip/hip_runtime.h>
#include <math.h>

#define NNODES 50000
#define NEDGES 400000
// MUL0=16, MUL1=8, IN_DIM=40, EDGE_FEAT=32
// w layout: w00 [0,256) (16x16), w10 [256,320) (8x8), w01 [320,448) (16x8), w11 [448,576) (8x16)

#define ALPHA0f    0.20412414523193154f   // sqrt(1/24); also == ALPHA1*INV_SQRT3
#define INV_SQRT3f 0.57735026918962576f

__device__ __forceinline__ float softplus_f(float x) {
    // jax.nn.softplus = logaddexp(x, 0) = max(x,0) + log1p(exp(-|x|))
    return fmaxf(x, 0.0f) + log1pf(expf(-fabsf(x)));
}

__device__ __forceinline__ void stage_w2(float* buf, const float* __restrict__ w2,
                                         int col0, int C, int log2C, int tid) {
    // buf[cl*32 + k] = w2[k*576 + col0 + cl]; coalesced global reads (cl fast across lanes)
    for (int i = tid; i < C * 32; i += 256) {
        int cl = i & (C - 1);
        int k  = i >> log2C;
        buf[cl * 32 + k] = w2[(size_t)k * 576 + col0 + cl];
    }
}

__device__ __forceinline__ float wcol_dot(const float* buf, const float* h, int cl, float bias) {
    const float4* col = (const float4*)(buf + cl * 32);
    float val = bias;
#pragma unroll
    for (int k4 = 0; k4 < 8; ++k4) {
        float4 wv = col[k4];                 // broadcast LDS read (uniform addr)
        val = fmaf(h[k4 * 4 + 0], wv.x, val);
        val = fmaf(h[k4 * 4 + 1], wv.y, val);
        val = fmaf(h[k4 * 4 + 2], wv.z, val);
        val = fmaf(h[k4 * 4 + 3], wv.w, val);
    }
    return val;
}

extern "C" __global__ __launch_bounds__(256)
void tp_edge_kernel(const float* __restrict__ node_attr,
                    const int*   __restrict__ edge_index,
                    const float* __restrict__ edge_attr,
                    const float* __restrict__ edge_sh,
                    const float* __restrict__ w1,
                    const float* __restrict__ b1,
                    const float* __restrict__ w2,
                    const float* __restrict__ b2,
                    float* __restrict__ summed,
                    float* __restrict__ counts)
{
    __shared__ float buf[8192];    // 32 KB: phase1 edge_attr tile [32][256], then w2 sections [C][32]
    __shared__ float w1s[1024];
    __shared__ float b1s[32];
    __shared__ float b2s[576];

    const int tid   = threadIdx.x;
    const int base  = blockIdx.x * 256;
    const int e     = base + tid;
    const bool alive = (e < NEDGES);
    const int esafe = alive ? e : 0;

    for (int i = tid; i < 1024; i += 256) w1s[i] = w1[i];
    if (tid < 32) b1s[tid] = b1[tid];
    for (int i = tid; i < 576; i += 256) b2s[i] = b2[i];

    // ---- stage edge_attr rows (transposed [k][t], conflict-free stores) ----
    {
        const float4* row = (const float4*)(edge_attr + (size_t)esafe * 32);
#pragma unroll
        for (int c = 0; c < 8; ++c) {
            float4 v = row[c];
            buf[(c * 4 + 0) * 256 + tid] = v.x;
            buf[(c * 4 + 1) * 256 + tid] = v.y;
            buf[(c * 4 + 2) * 256 + tid] = v.z;
            buf[(c * 4 + 3) * 256 + tid] = v.w;
        }
    }
    __syncthreads();

    // ---- phase 1: h = softplus(edge_attr @ w1 + b1) ----
    float h[32];
    {
        float acc[32];
#pragma unroll
        for (int j = 0; j < 32; ++j) acc[j] = b1s[j];
#pragma unroll 1
        for (int k = 0; k < 32; ++k) {
            float ea = buf[k * 256 + tid];     // conflict-free: consecutive lanes, consecutive banks
            const float4* w1r = (const float4*)(w1s + k * 32);
#pragma unroll
            for (int j4 = 0; j4 < 8; ++j4) {
                float4 wv = w1r[j4];           // broadcast
                acc[j4 * 4 + 0] = fmaf(ea, wv.x, acc[j4 * 4 + 0]);
                acc[j4 * 4 + 1] = fmaf(ea, wv.y, acc[j4 * 4 + 1]);
                acc[j4 * 4 + 2] = fmaf(ea, wv.z, acc[j4 * 4 + 2]);
                acc[j4 * 4 + 3] = fmaf(ea, wv.w, acc[j4 * 4 + 3]);
            }
        }
#pragma unroll
        for (int j = 0; j < 32; ++j) h[j] = softplus_f(acc[j]);
    }

    // ---- per-edge metadata ----
    const int src = edge_index[esafe];
    const int dst = edge_index[NEDGES + esafe];
    const float4 sh = *(const float4*)(edge_sh + (size_t)esafe * 4);
    const float y0 = sh.x, y1x = sh.y, y1y = sh.z, y1z = sh.w;
    const float* xrow = node_attr + (size_t)dst * 40;

    float acc0[16];   // out0 accumulator (w00 with s0*y0, w11 with INV_SQRT3*b)
    float acc1[24];   // out1: sum_u (y0*v1[u,m]) * w10[u,w]   -> [w*3+m]
    float r01[8];     // sum_u s0[u] * w01[u,w]
#pragma unroll
    for (int i = 0; i < 16; ++i) acc0[i] = 0.0f;
#pragma unroll
    for (int i = 0; i < 24; ++i) acc1[i] = 0.0f;
#pragma unroll
    for (int i = 0; i < 8; ++i)  r01[i]  = 0.0f;

    // ---- section A: w00 (cols 0..255), out0 += (s0[u]*y0) * w00[u,w] ----
    __syncthreads();
    stage_w2(buf, w2, 0, 256, 8, tid);
    __syncthreads();
#pragma unroll 1
    for (int u = 0; u < 16; ++u) {
        float s0u = xrow[u] * y0;
#pragma unroll
        for (int w = 0; w < 16; ++w) {
            int cl = u * 16 + w;
            float val = wcol_dot(buf, h, cl, b2s[cl]);
            acc0[w] = fmaf(s0u, val, acc0[w]);
        }
    }

    // ---- section B: w10 (cols 256..319), acc1[w*3+m] += (y0*v1[u,m]) * w10[u,w] ----
    __syncthreads();
    stage_w2(buf, w2, 256, 64, 6, tid);
    __syncthreads();
#pragma unroll 1
    for (int u = 0; u < 8; ++u) {
        float va = xrow[16 + u * 3 + 0] * y0;
        float vb = xrow[16 + u * 3 + 1] * y0;
        float vc = xrow[16 + u * 3 + 2] * y0;
#pragma unroll
        for (int w = 0; w < 8; ++w) {
            int cl = u * 8 + w;
            float val = wcol_dot(buf, h, cl, b2s[256 + cl]);
            acc1[w * 3 + 0] = fmaf(va, val, acc1[w * 3 + 0]);
            acc1[w * 3 + 1] = fmaf(vb, val, acc1[w * 3 + 1]);
            acc1[w * 3 + 2] = fmaf(vc, val, acc1[w * 3 + 2]);
        }
    }

    // ---- section C: w01 (cols 320..447), r01[w] += s0[u] * w01[u,w] ----
    __syncthreads();
    stage_w2(buf, w2, 320, 128, 7, tid);
    __syncthreads();
#pragma unroll 1
    for (int u = 0; u < 16; ++u) {
        float s0u = xrow[u];
#pragma unroll
        for (int w = 0; w < 8; ++w) {
            int cl = u * 8 + w;
            float val = wcol_dot(buf, h, cl, b2s[320 + cl]);
            r01[w] = fmaf(s0u, val, r01[w]);
        }
    }

    // ---- section D: w11 (cols 448..575), acc0[w] += (INV_SQRT3 * sum_m v1[u,m]*y1[m]) * w11[u,w] ----
    __syncthreads();
    stage_w2(buf, w2, 448, 128, 7, tid);
    __syncthreads();
#pragma unroll 1
    for (int u = 0; u < 8; ++u) {
        float va = xrow[16 + u * 3 + 0];
        float vb = xrow[16 + u * 3 + 1];
        float vc = xrow[16 + u * 3 + 2];
        float bu = (va * y1x + vb * y1y + vc * y1z) * INV_SQRT3f;
#pragma unroll
        for (int w = 0; w < 16; ++w) {
            int cl = u * 16 + w;
            float val = wcol_dot(buf, h, cl, b2s[448 + cl]);
            acc0[w] = fmaf(bu, val, acc0[w]);
        }
    }

    // ---- epilogue: tp + atomic scatter ----
    if (alive) {
        float tp[40];
#pragma unroll
        for (int w = 0; w < 16; ++w) tp[w] = ALPHA0f * acc0[w];
#pragma unroll
        for (int w = 0; w < 8; ++w) {
            // ALPHA1*INV_SQRT3 == ALPHA0
            tp[16 + w * 3 + 0] = ALPHA0f * (acc1[w * 3 + 0] + y1x * r01[w]);
            tp[16 + w * 3 + 1] = ALPHA0f * (acc1[w * 3 + 1] + y1y * r01[w]);
            tp[16 + w * 3 + 2] = ALPHA0f * (acc1[w * 3 + 2] + y1z * r01[w]);
        }
        float* srow = summed + (size_t)src * 40;
#pragma unroll
        for (int j = 0; j < 40; ++j) atomicAdd(&srow[j], tp[j]);
        atomicAdd(&counts[src], 1.0f);
    }
}

extern "C" __global__ __launch_bounds__(256)
void finalize_kernel(const float* __restrict__ summed,
                     const float* __restrict__ counts,
                     const float* __restrict__ node_attr,
                     float* __restrict__ out)
{
    int idx = blockIdx.x * 256 + threadIdx.x;
    if (idx < NNODES * 40) {
        int n = idx / 40;
        float c = fmaxf(counts[n], 1.0f);
        out[idx] = summed[idx] / c + node_attr[idx];
    }
}

extern "C" void kernel_launch(void* const* d_in, const int* in_sizes, int n_in,
                              void* d_out, int out_size, void* d_ws, size_t ws_size,
                              hipStream_t stream)
{
    const float* node_attr  = (const float*)d_in[0];
    const int*   edge_index = (const int*)  d_in[1];
    const float* edge_attr  = (const float*)d_in[2];
    const float* edge_sh    = (const float*)d_in[3];
    const float* w1 = (const float*)d_in[4];
    const float* b1 = (const float*)d_in[5];
    const float* w2 = (const float*)d_in[6];
    const float* b2 = (const float*)d_in[7];
    float* out    = (float*)d_out;
    float* summed = (float*)d_ws;                  // NNODES*40 floats
    float* counts = summed + (size_t)NNODES * 40;  // NNODES floats

    hipMemsetAsync(d_ws, 0, (size_t)(NNODES * 40 + NNODES) * sizeof(float), stream);

    int nblk = (NEDGES + 255) / 256;
    hipLaunchKernelGGL(tp_edge_kernel, dim3(nblk), dim3(256), 0, stream,
                       node_attr, edge_index, edge_attr, edge_sh, w1, b1, w2, b2,
                       summed, counts);

    int fblk = (NNODES * 40 + 255) / 256;
    hipLaunchKernelGGL(finalize_kernel, dim3(fblk), dim3(256), 0, stream,
                       summed, counts, node_attr, out);
}

// Round 2
// 229.936 us; speedup vs baseline: 7.4236x; 7.4236x over previous
//
#include <hip/hip_runtime.h>
#include <hip/hip_bf16.h>
#include <math.h>

#define NNODES 50000
#define NEDGES 400000
// MUL0=16, MUL1=8, IN_DIM=40; w2 cols: w00 [0,256) w10 [256,320) w01 [320,448) w11 [448,576)
#define ALPHA0f    0.20412414523193154f   // sqrt(1/24) == ALPHA1*INV_SQRT3
#define INV_SQRT3f 0.57735026918962576f

typedef short bf16x8 __attribute__((ext_vector_type(8)));   // 8 bf16 in 4 VGPRs (guide-verified)
typedef float f32x4  __attribute__((ext_vector_type(4)));

__device__ __forceinline__ short f2bf(float x) {
    __hip_bfloat16 h = __float2bfloat16(x);
    return *reinterpret_cast<short*>(&h);
}

__device__ __forceinline__ float softplus_f(float x) {
    return fmaxf(x, 0.0f) + log1pf(expf(-fabsf(x)));
}

// Fragment layouts for v_mfma_f32_16x16x32_bf16 (D = A[16x32] * B[32x16]):
//   A: lane l holds row = l&15,  k = (l>>4)*8 + j, j=0..7 (contiguous K)
//   B: lane l holds col = l&15,  k = (l>>4)*8 + j
//   C/D: lane l holds col = l&15, row = (l>>4)*4 + r   [verified m89/m91]
__global__ __launch_bounds__(512)
void tp_mfma_kernel(const float* __restrict__ node_attr,
                    const int*   __restrict__ edge_index,
                    const float* __restrict__ edge_attr,
                    const float* __restrict__ edge_sh,
                    const float* __restrict__ w1,
                    const float* __restrict__ b1,
                    const float* __restrict__ w2,
                    const float* __restrict__ b2,
                    float* __restrict__ summed,
                    float* __restrict__ counts)
{
    __shared__ short w2f[36 * 512];      // [tile][lane][8] bf16 fragments of w2
    __shared__ short w1f[2 * 512];       // [tile][lane][8] bf16 fragments of w1
    __shared__ float b1s[32];
    __shared__ float b2s[576];
    __shared__ float xs[8][16][44];      // per-wave: gathered node rows [40] + sh [40..43]
    __shared__ short hs[8][16][48];      // per-wave: h rows, padded to 48 bf16 (96B, 16B-aligned)
    __shared__ int   dsts[8][16];

    const int tid = threadIdx.x;

    // ---- stage weights into fragment layout (once per block) ----
    for (int i = tid; i < 36 * 512; i += 512) {
        int col = i % 576, k = i / 576;                 // coalesced read of w2[k][col]
        int t = col >> 4, lr = col & 15, lg = k >> 3, j = k & 7;
        int lanei = lr | (lg << 4);
        w2f[(t * 64 + lanei) * 8 + j] = f2bf(w2[i]);
    }
    for (int i = tid; i < 1024; i += 512) {
        int col = i & 31, k = i >> 5;
        int t = col >> 4, lr = col & 15, lg = k >> 3, j = k & 7;
        int lanei = lr | (lg << 4);
        w1f[(t * 64 + lanei) * 8 + j] = f2bf(w1[i]);
    }
    if (tid < 32) b1s[tid] = b1[tid];
    for (int i = tid; i < 576; i += 512) b2s[i] = b2[i];
    __syncthreads();

    const int wid  = tid >> 6, lane = tid & 63;
    const int lrow = lane & 15, lgrp = lane >> 4;

    const bf16x8 wfr0 = *reinterpret_cast<const bf16x8*>(&w1f[lane * 8]);
    const bf16x8 wfr1 = *reinterpret_cast<const bf16x8*>(&w1f[512 + lane * 8]);
    const float b1a = b1s[lrow], b1b = b1s[16 + lrow];
    const f32x4 zero = {0.f, 0.f, 0.f, 0.f};

    for (int g = blockIdx.x; g < NEDGES / 128; g += gridDim.x) {
        const int e0 = g * 128 + wid * 16;             // this wave's 16 edges (exact: 400000%128==0)

        // ---- stage dst indices + edge_sh ----
        if (lane < 16) {
            int d = edge_index[NEDGES + e0 + lane];
            dsts[wid][lane] = d;
            float4 sh = *(const float4*)(edge_sh + (size_t)(e0 + lane) * 4);
            xs[wid][lane][40] = sh.x; xs[wid][lane][41] = sh.y;
            xs[wid][lane][42] = sh.z; xs[wid][lane][43] = sh.w;
        }
        // ---- gather x = node_attr[dst] rows (16 x 40 floats = 160 float4) ----
        #pragma unroll
        for (int it = 0; it < 3; ++it) {
            int idx = it * 64 + lane;
            if (idx < 160) {
                int ed = idx / 10, part = idx % 10;
                int d = dsts[wid][ed];
                float4 v = *(const float4*)(node_attr + (size_t)d * 40 + part * 4);
                *(float4*)&xs[wid][ed][part * 4] = v;
            }
        }

        // ---- GEMM1: h = softplus(edge_attr @ w1 + b1), A from global, coalesced ----
        const float4* ear = (const float4*)(edge_attr + (size_t)(e0 + lrow) * 32 + lgrp * 8);
        float4 ea0 = ear[0], ea1 = ear[1];
        bf16x8 a1;
        a1[0] = f2bf(ea0.x); a1[1] = f2bf(ea0.y); a1[2] = f2bf(ea0.z); a1[3] = f2bf(ea0.w);
        a1[4] = f2bf(ea1.x); a1[5] = f2bf(ea1.y); a1[6] = f2bf(ea1.z); a1[7] = f2bf(ea1.w);
        f32x4 c0 = __builtin_amdgcn_mfma_f32_16x16x32_bf16(a1, wfr0, zero, 0, 0, 0);
        f32x4 c1 = __builtin_amdgcn_mfma_f32_16x16x32_bf16(a1, wfr1, zero, 0, 0, 0);
        #pragma unroll
        for (int r = 0; r < 4; ++r) {
            hs[wid][lgrp * 4 + r][lrow]      = f2bf(softplus_f(c0[r] + b1a));
            hs[wid][lgrp * 4 + r][16 + lrow] = f2bf(softplus_f(c1[r] + b1b));
        }
        // ---- A-fragment of h (transpose through LDS, one b128) ----
        bf16x8 a2 = *reinterpret_cast<const bf16x8*>(&hs[wid][lrow][lgrp * 8]);

        // ---- per-lane per-edge constants (4 edges: er = lgrp*4 + r) ----
        float y0v[4], y1xv[4], y1yv[4], y1zv[4]; int srcs[4];
        #pragma unroll
        for (int r = 0; r < 4; ++r) {
            int er = lgrp * 4 + r;
            y0v[r]  = xs[wid][er][40]; y1xv[r] = xs[wid][er][41];
            y1yv[r] = xs[wid][er][42]; y1zv[r] = xs[wid][er][43];
            srcs[r] = edge_index[e0 + er];
        }

        f32x4 acc0 = zero, am0 = zero, am1 = zero, am2 = zero, r01 = zero;

        // ---- w00 tiles 0..15: col = u*16 + w, tile t => u=t, w=lrow ----
        #pragma unroll
        for (int t = 0; t < 16; ++t) {
            bf16x8 bfr = *reinterpret_cast<const bf16x8*>(&w2f[(t * 64 + lane) * 8]);
            f32x4 wv = __builtin_amdgcn_mfma_f32_16x16x32_bf16(a2, bfr, zero, 0, 0, 0);
            float b2v = b2s[t * 16 + lrow];
            #pragma unroll
            for (int r = 0; r < 4; ++r) {
                float f = xs[wid][lgrp * 4 + r][t] * y0v[r];
                acc0[r] += f * (wv[r] + b2v);
            }
        }
        const int uh = lrow >> 3;
        // ---- w10 tiles 16..19: local col = u*8 + w, u = 2*tt + (lrow>>3), w = lrow&7 ----
        #pragma unroll
        for (int tt = 0; tt < 4; ++tt) {
            int t = 16 + tt;
            bf16x8 bfr = *reinterpret_cast<const bf16x8*>(&w2f[(t * 64 + lane) * 8]);
            f32x4 wv = __builtin_amdgcn_mfma_f32_16x16x32_bf16(a2, bfr, zero, 0, 0, 0);
            float b2v = b2s[t * 16 + lrow];
            int u = 2 * tt + uh;
            #pragma unroll
            for (int r = 0; r < 4; ++r) {
                float wval = (wv[r] + b2v) * y0v[r];
                int er = lgrp * 4 + r;
                am0[r] += xs[wid][er][16 + u * 3 + 0] * wval;
                am1[r] += xs[wid][er][16 + u * 3 + 1] * wval;
                am2[r] += xs[wid][er][16 + u * 3 + 2] * wval;
            }
        }
        // ---- w01 tiles 20..27: u = 2*tt + uh, w = lrow&7; r01 = sum_u s0[u]*w01[u,w] ----
        #pragma unroll
        for (int tt = 0; tt < 8; ++tt) {
            int t = 20 + tt;
            bf16x8 bfr = *reinterpret_cast<const bf16x8*>(&w2f[(t * 64 + lane) * 8]);
            f32x4 wv = __builtin_amdgcn_mfma_f32_16x16x32_bf16(a2, bfr, zero, 0, 0, 0);
            float b2v = b2s[t * 16 + lrow];
            int u = 2 * tt + uh;
            #pragma unroll
            for (int r = 0; r < 4; ++r)
                r01[r] += xs[wid][lgrp * 4 + r][u] * (wv[r] + b2v);
        }
        // ---- w11 tiles 28..35: u = tt, w = lrow; acc0 += INV_SQRT3*(v1[u].y1)*w11[u,w] ----
        #pragma unroll
        for (int tt = 0; tt < 8; ++tt) {
            int t = 28 + tt;
            bf16x8 bfr = *reinterpret_cast<const bf16x8*>(&w2f[(t * 64 + lane) * 8]);
            f32x4 wv = __builtin_amdgcn_mfma_f32_16x16x32_bf16(a2, bfr, zero, 0, 0, 0);
            float b2v = b2s[t * 16 + lrow];
            #pragma unroll
            for (int r = 0; r < 4; ++r) {
                int er = lgrp * 4 + r;
                float bu = INV_SQRT3f * (xs[wid][er][16 + tt * 3 + 0] * y1xv[r] +
                                         xs[wid][er][16 + tt * 3 + 1] * y1yv[r] +
                                         xs[wid][er][16 + tt * 3 + 2] * y1zv[r]);
                acc0[r] += bu * (wv[r] + b2v);
            }
        }

        // ---- reduce the two u-halves (lanes l and l^8 hold same w) ----
        #pragma unroll
        for (int r = 0; r < 4; ++r) {
            am0[r] += __shfl_xor(am0[r], 8);
            am1[r] += __shfl_xor(am1[r], 8);
            am2[r] += __shfl_xor(am2[r], 8);
            r01[r] += __shfl_xor(r01[r], 8);
        }

        // ---- scatter ----
        #pragma unroll
        for (int r = 0; r < 4; ++r)
            atomicAdd(&summed[(size_t)srcs[r] * 40 + lrow], ALPHA0f * acc0[r]);
        if (lrow < 8) {
            #pragma unroll
            for (int r = 0; r < 4; ++r) {
                float* p = &summed[(size_t)srcs[r] * 40 + 16 + lrow * 3];
                atomicAdd(p + 0, ALPHA0f * (am0[r] + y1xv[r] * r01[r]));
                atomicAdd(p + 1, ALPHA0f * (am1[r] + y1yv[r] * r01[r]));
                atomicAdd(p + 2, ALPHA0f * (am2[r] + y1zv[r] * r01[r]));
            }
        }
        if (lrow == 0) {
            #pragma unroll
            for (int r = 0; r < 4; ++r) atomicAdd(&counts[srcs[r]], 1.0f);
        }
    }
}

extern "C" __global__ __launch_bounds__(256)
void finalize_kernel(const float* __restrict__ summed,
                     const float* __restrict__ counts,
                     const float* __restrict__ node_attr,
                     float* __restrict__ out)
{
    int idx = blockIdx.x * 256 + threadIdx.x;
    if (idx < NNODES * 40) {
        int n = idx / 40;
        float c = fmaxf(counts[n], 1.0f);
        out[idx] = summed[idx] / c + node_attr[idx];
    }
}

extern "C" void kernel_launch(void* const* d_in, const int* in_sizes, int n_in,
                              void* d_out, int out_size, void* d_ws, size_t ws_size,
                              hipStream_t stream)
{
    const float* node_attr  = (const float*)d_in[0];
    const int*   edge_index = (const int*)  d_in[1];
    const float* edge_attr  = (const float*)d_in[2];
    const float* edge_sh    = (const float*)d_in[3];
    const float* w1 = (const float*)d_in[4];
    const float* b1 = (const float*)d_in[5];
    const float* w2 = (const float*)d_in[6];
    const float* b2 = (const float*)d_in[7];
    float* out    = (float*)d_out;
    float* summed = (float*)d_ws;                  // NNODES*40 floats
    float* counts = summed + (size_t)NNODES * 40;  // NNODES floats

    hipMemsetAsync(d_ws, 0, (size_t)(NNODES * 40 + NNODES) * sizeof(float), stream);

    hipLaunchKernelGGL(tp_mfma_kernel, dim3(512), dim3(512), 0, stream,
                       node_attr, edge_index, edge_attr, edge_sh, w1, b1, w2, b2,
                       summed, counts);

    int fblk = (NNODES * 40 + 255) / 256;
    hipLaunchKernelGGL(finalize_kernel, dim3(fblk), dim3(256), 0, stream,
                       summed, counts, node_attr, out);
}

// Round 3
// 179.644 us; speedup vs baseline: 9.5019x; 1.2800x over previous
//
#include <hip/hip_runtime.h>
#include <hip/hip_bf16.h>
#include <math.h>

#define NNODES 50000
#define NEDGES 400000
// MUL0=16, MUL1=8, IN_DIM=40; w2 cols: w00 [0,256) w10 [256,320) w01 [320,448) w11 [448,576)
#define ALPHA0f    0.20412414523193154f   // sqrt(1/24) == ALPHA1*INV_SQRT3
#define INV_SQRT3f 0.57735026918962576f

typedef short bf16x8 __attribute__((ext_vector_type(8)));
typedef float f32x4  __attribute__((ext_vector_type(4)));

__device__ __forceinline__ short f2bf(float x) {
    __hip_bfloat16 h = __float2bfloat16(x);
    return *reinterpret_cast<short*>(&h);
}

__device__ __forceinline__ float softplus_f(float x) {
    return fmaxf(x, 0.0f) + log1pf(expf(-fabsf(x)));
}

// MODE 0: atomic scatter into summed/counts (fallback if ws too small)
// MODE 1: store tp rows to ws + int histogram of src
template<int MODE>
__global__ __launch_bounds__(512)
void tp_mfma_kernel(const float* __restrict__ node_attr,
                    const int*   __restrict__ edge_index,
                    const float* __restrict__ edge_attr,
                    const float* __restrict__ edge_sh,
                    const float* __restrict__ w1,
                    const float* __restrict__ b1,
                    const float* __restrict__ w2,
                    const float* __restrict__ b2,
                    float* __restrict__ summed,   // MODE0
                    float* __restrict__ counts,   // MODE0
                    float* __restrict__ tp_out,   // MODE1
                    int*   __restrict__ counts_i) // MODE1
{
    __shared__ short w2f[36 * 512];
    __shared__ short w1f[2 * 512];
    __shared__ float b1s[32];
    __shared__ float b2s[576];
    __shared__ float xs[8][16][44];
    __shared__ short hs[8][16][48];
    __shared__ int   dsts[8][16];

    const int tid = threadIdx.x;

    for (int i = tid; i < 36 * 512; i += 512) {
        int col = i % 576, k = i / 576;
        int t = col >> 4, lr = col & 15, lg = k >> 3, j = k & 7;
        w2f[((t * 64 + (lr | (lg << 4))) * 8) + j] = f2bf(w2[i]);
    }
    for (int i = tid; i < 1024; i += 512) {
        int col = i & 31, k = i >> 5;
        int t = col >> 4, lr = col & 15, lg = k >> 3, j = k & 7;
        w1f[((t * 64 + (lr | (lg << 4))) * 8) + j] = f2bf(w1[i]);
    }
    if (tid < 32) b1s[tid] = b1[tid];
    for (int i = tid; i < 576; i += 512) b2s[i] = b2[i];
    __syncthreads();

    const int wid  = tid >> 6, lane = tid & 63;
    const int lrow = lane & 15, lgrp = lane >> 4;

    const bf16x8 wfr0 = *reinterpret_cast<const bf16x8*>(&w1f[lane * 8]);
    const bf16x8 wfr1 = *reinterpret_cast<const bf16x8*>(&w1f[512 + lane * 8]);
    const float b1a = b1s[lrow], b1b = b1s[16 + lrow];
    const f32x4 zero = {0.f, 0.f, 0.f, 0.f};

    for (int g = blockIdx.x; g < NEDGES / 128; g += gridDim.x) {
        const int e0 = g * 128 + wid * 16;

        if (lane < 16) {
            int d = edge_index[NEDGES + e0 + lane];
            dsts[wid][lane] = d;
            float4 sh = *(const float4*)(edge_sh + (size_t)(e0 + lane) * 4);
            xs[wid][lane][40] = sh.x; xs[wid][lane][41] = sh.y;
            xs[wid][lane][42] = sh.z; xs[wid][lane][43] = sh.w;
        }
        #pragma unroll
        for (int it = 0; it < 3; ++it) {
            int idx = it * 64 + lane;
            if (idx < 160) {
                int ed = idx / 10, part = idx % 10;
                int d = dsts[wid][ed];
                float4 v = *(const float4*)(node_attr + (size_t)d * 40 + part * 4);
                *(float4*)&xs[wid][ed][part * 4] = v;
            }
        }

        const float4* ear = (const float4*)(edge_attr + (size_t)(e0 + lrow) * 32 + lgrp * 8);
        float4 ea0 = ear[0], ea1 = ear[1];
        bf16x8 a1;
        a1[0] = f2bf(ea0.x); a1[1] = f2bf(ea0.y); a1[2] = f2bf(ea0.z); a1[3] = f2bf(ea0.w);
        a1[4] = f2bf(ea1.x); a1[5] = f2bf(ea1.y); a1[6] = f2bf(ea1.z); a1[7] = f2bf(ea1.w);
        f32x4 c0 = __builtin_amdgcn_mfma_f32_16x16x32_bf16(a1, wfr0, zero, 0, 0, 0);
        f32x4 c1 = __builtin_amdgcn_mfma_f32_16x16x32_bf16(a1, wfr1, zero, 0, 0, 0);
        #pragma unroll
        for (int r = 0; r < 4; ++r) {
            hs[wid][lgrp * 4 + r][lrow]      = f2bf(softplus_f(c0[r] + b1a));
            hs[wid][lgrp * 4 + r][16 + lrow] = f2bf(softplus_f(c1[r] + b1b));
        }
        bf16x8 a2 = *reinterpret_cast<const bf16x8*>(&hs[wid][lrow][lgrp * 8]);

        float y0v[4], y1xv[4], y1yv[4], y1zv[4]; int srcs[4];
        #pragma unroll
        for (int r = 0; r < 4; ++r) {
            int er = lgrp * 4 + r;
            y0v[r]  = xs[wid][er][40]; y1xv[r] = xs[wid][er][41];
            y1yv[r] = xs[wid][er][42]; y1zv[r] = xs[wid][er][43];
            srcs[r] = edge_index[e0 + er];
        }

        f32x4 acc0 = zero, am0 = zero, am1 = zero, am2 = zero, r01 = zero;

        #pragma unroll
        for (int t = 0; t < 16; ++t) {
            bf16x8 bfr = *reinterpret_cast<const bf16x8*>(&w2f[(t * 64 + lane) * 8]);
            f32x4 wv = __builtin_amdgcn_mfma_f32_16x16x32_bf16(a2, bfr, zero, 0, 0, 0);
            float b2v = b2s[t * 16 + lrow];
            #pragma unroll
            for (int r = 0; r < 4; ++r) {
                float f = xs[wid][lgrp * 4 + r][t] * y0v[r];
                acc0[r] += f * (wv[r] + b2v);
            }
        }
        const int uh = lrow >> 3;
        #pragma unroll
        for (int tt = 0; tt < 4; ++tt) {
            int t = 16 + tt;
            bf16x8 bfr = *reinterpret_cast<const bf16x8*>(&w2f[(t * 64 + lane) * 8]);
            f32x4 wv = __builtin_amdgcn_mfma_f32_16x16x32_bf16(a2, bfr, zero, 0, 0, 0);
            float b2v = b2s[t * 16 + lrow];
            int u = 2 * tt + uh;
            #pragma unroll
            for (int r = 0; r < 4; ++r) {
                float wval = (wv[r] + b2v) * y0v[r];
                int er = lgrp * 4 + r;
                am0[r] += xs[wid][er][16 + u * 3 + 0] * wval;
                am1[r] += xs[wid][er][16 + u * 3 + 1] * wval;
                am2[r] += xs[wid][er][16 + u * 3 + 2] * wval;
            }
        }
        #pragma unroll
        for (int tt = 0; tt < 8; ++tt) {
            int t = 20 + tt;
            bf16x8 bfr = *reinterpret_cast<const bf16x8*>(&w2f[(t * 64 + lane) * 8]);
            f32x4 wv = __builtin_amdgcn_mfma_f32_16x16x32_bf16(a2, bfr, zero, 0, 0, 0);
            float b2v = b2s[t * 16 + lrow];
            int u = 2 * tt + uh;
            #pragma unroll
            for (int r = 0; r < 4; ++r)
                r01[r] += xs[wid][lgrp * 4 + r][u] * (wv[r] + b2v);
        }
        #pragma unroll
        for (int tt = 0; tt < 8; ++tt) {
            int t = 28 + tt;
            bf16x8 bfr = *reinterpret_cast<const bf16x8*>(&w2f[(t * 64 + lane) * 8]);
            f32x4 wv = __builtin_amdgcn_mfma_f32_16x16x32_bf16(a2, bfr, zero, 0, 0, 0);
            float b2v = b2s[t * 16 + lrow];
            #pragma unroll
            for (int r = 0; r < 4; ++r) {
                int er = lgrp * 4 + r;
                float bu = INV_SQRT3f * (xs[wid][er][16 + tt * 3 + 0] * y1xv[r] +
                                         xs[wid][er][16 + tt * 3 + 1] * y1yv[r] +
                                         xs[wid][er][16 + tt * 3 + 2] * y1zv[r]);
                acc0[r] += bu * (wv[r] + b2v);
            }
        }

        #pragma unroll
        for (int r = 0; r < 4; ++r) {
            am0[r] += __shfl_xor(am0[r], 8);
            am1[r] += __shfl_xor(am1[r], 8);
            am2[r] += __shfl_xor(am2[r], 8);
            r01[r] += __shfl_xor(r01[r], 8);
        }

        if (MODE == 0) {
            #pragma unroll
            for (int r = 0; r < 4; ++r)
                atomicAdd(&summed[(size_t)srcs[r] * 40 + lrow], ALPHA0f * acc0[r]);
            if (lrow < 8) {
                #pragma unroll
                for (int r = 0; r < 4; ++r) {
                    float* p = &summed[(size_t)srcs[r] * 40 + 16 + lrow * 3];
                    atomicAdd(p + 0, ALPHA0f * (am0[r] + y1xv[r] * r01[r]));
                    atomicAdd(p + 1, ALPHA0f * (am1[r] + y1yv[r] * r01[r]));
                    atomicAdd(p + 2, ALPHA0f * (am2[r] + y1zv[r] * r01[r]));
                }
            }
            if (lrow == 0) {
                #pragma unroll
                for (int r = 0; r < 4; ++r) atomicAdd(&counts[srcs[r]], 1.0f);
            }
        } else {
            #pragma unroll
            for (int r = 0; r < 4; ++r)
                tp_out[(size_t)(e0 + lgrp * 4 + r) * 40 + lrow] = ALPHA0f * acc0[r];
            if (lrow < 8) {
                #pragma unroll
                for (int r = 0; r < 4; ++r) {
                    float* p = &tp_out[(size_t)(e0 + lgrp * 4 + r) * 40 + 16 + lrow * 3];
                    p[0] = ALPHA0f * (am0[r] + y1xv[r] * r01[r]);
                    p[1] = ALPHA0f * (am1[r] + y1yv[r] * r01[r]);
                    p[2] = ALPHA0f * (am2[r] + y1zv[r] * r01[r]);
                }
            }
            if (lrow == 0) {
                #pragma unroll
                for (int r = 0; r < 4; ++r) atomicAdd(&counts_i[srcs[r]], 1);
            }
        }
    }
}

// ---- CSR build: per-block exclusive scan of counts ----
extern "C" __global__ __launch_bounds__(256)
void scanA_kernel(const int* __restrict__ counts_i, int* __restrict__ offsets,
                  int* __restrict__ bsums)
{
    __shared__ int s[256];
    int t = threadIdx.x, id = blockIdx.x * 256 + t;
    int c = (id < NNODES) ? counts_i[id] : 0;
    s[t] = c; __syncthreads();
    #pragma unroll
    for (int off = 1; off < 256; off <<= 1) {
        int v = (t >= off) ? s[t - off] : 0;
        __syncthreads();
        s[t] += v;
        __syncthreads();
    }
    if (id < NNODES) offsets[id] = s[t] - c;
    if (t == 255) bsums[blockIdx.x] = s[255];
}

extern "C" __global__ __launch_bounds__(256)
void scanB_kernel(int* __restrict__ bsums, int nblocks)
{
    __shared__ int s[256];
    int t = threadIdx.x;
    int c = (t < nblocks) ? bsums[t] : 0;
    s[t] = c; __syncthreads();
    #pragma unroll
    for (int off = 1; off < 256; off <<= 1) {
        int v = (t >= off) ? s[t - off] : 0;
        __syncthreads();
        s[t] += v;
        __syncthreads();
    }
    if (t < nblocks) bsums[t] = s[t] - c;
}

extern "C" __global__ __launch_bounds__(256)
void scanC_kernel(int* __restrict__ offsets, const int* __restrict__ bsums,
                  int* __restrict__ cursor)
{
    int id = blockIdx.x * 256 + threadIdx.x;
    if (id < NNODES) {
        int o = offsets[id] + bsums[id >> 8];
        offsets[id] = o;
        cursor[id] = o;
    }
}

extern "C" __global__ __launch_bounds__(256)
void scatter_kernel(const int* __restrict__ edge_index, int* __restrict__ cursor,
                    int* __restrict__ csr)
{
    int e = blockIdx.x * 256 + threadIdx.x;
    if (e < NEDGES) {
        int src = edge_index[e];
        int pos = atomicAdd(&cursor[src], 1);
        csr[pos] = e;
    }
}

// ---- segmented mean + residual: one wave per node ----
extern "C" __global__ __launch_bounds__(256)
void gather_kernel(const float* __restrict__ tp, const int* __restrict__ offsets,
                   const int* __restrict__ csr, const float* __restrict__ node_attr,
                   float* __restrict__ out)
{
    int gw = (blockIdx.x * 256 + threadIdx.x) >> 6;
    int lane = threadIdx.x & 63;
    int nwaves = (gridDim.x * 256) >> 6;
    for (int n = gw; n < NNODES; n += nwaves) {
        int start = offsets[n];
        int end = (n == NNODES - 1) ? NEDGES : offsets[n + 1];
        float acc = 0.0f;
        for (int i0 = start; i0 < end; i0 += 8) {
            int ids[8];
            #pragma unroll
            for (int j = 0; j < 8; ++j) ids[j] = (i0 + j < end) ? csr[i0 + j] : -1;
            #pragma unroll
            for (int j = 0; j < 8; ++j)
                if (ids[j] >= 0 && lane < 40) acc += tp[(size_t)ids[j] * 40 + lane];
        }
        if (lane < 40) {
            float deg = (float)(end - start);
            out[(size_t)n * 40 + lane] = acc / fmaxf(deg, 1.0f) + node_attr[(size_t)n * 40 + lane];
        }
    }
}

extern "C" __global__ __launch_bounds__(256)
void finalize_kernel(const float* __restrict__ summed,
                     const float* __restrict__ counts,
                     const float* __restrict__ node_attr,
                     float* __restrict__ out)
{
    int idx = blockIdx.x * 256 + threadIdx.x;
    if (idx < NNODES * 40) {
        int n = idx / 40;
        float c = fmaxf(counts[n], 1.0f);
        out[idx] = summed[idx] / c + node_attr[idx];
    }
}

extern "C" void kernel_launch(void* const* d_in, const int* in_sizes, int n_in,
                              void* d_out, int out_size, void* d_ws, size_t ws_size,
                              hipStream_t stream)
{
    const float* node_attr  = (const float*)d_in[0];
    const int*   edge_index = (const int*)  d_in[1];
    const float* edge_attr  = (const float*)d_in[2];
    const float* edge_sh    = (const float*)d_in[3];
    const float* w1 = (const float*)d_in[4];
    const float* b1 = (const float*)d_in[5];
    const float* w2 = (const float*)d_in[6];
    const float* b2 = (const float*)d_in[7];
    float* out = (float*)d_out;

    const int SCAN_BLOCKS = (NNODES + 255) / 256;  // 196
    const size_t NEED = ((size_t)NEDGES * 40 + NEDGES + 3 * (size_t)NNODES + 256) * 4;

    if (ws_size >= NEED) {
        // fast path: tp store + CSR segmented mean
        float* tp       = (float*)d_ws;                    // NEDGES*40
        int*   counts_i = (int*)(tp + (size_t)NEDGES * 40);// NNODES
        int*   offsets  = counts_i + NNODES;               // NNODES
        int*   cursor   = offsets + NNODES;                // NNODES
        int*   csr      = cursor + NNODES;                 // NEDGES
        int*   bsums    = csr + NEDGES;                    // 256

        hipMemsetAsync(counts_i, 0, (size_t)NNODES * 4, stream);

        hipLaunchKernelGGL((tp_mfma_kernel<1>), dim3(512), dim3(512), 0, stream,
                           node_attr, edge_index, edge_attr, edge_sh, w1, b1, w2, b2,
                           (float*)nullptr, (float*)nullptr, tp, counts_i);

        hipLaunchKernelGGL(scanA_kernel, dim3(SCAN_BLOCKS), dim3(256), 0, stream,
                           counts_i, offsets, bsums);
        hipLaunchKernelGGL(scanB_kernel, dim3(1), dim3(256), 0, stream,
                           bsums, SCAN_BLOCKS);
        hipLaunchKernelGGL(scanC_kernel, dim3(SCAN_BLOCKS), dim3(256), 0, stream,
                           offsets, bsums, cursor);
        hipLaunchKernelGGL(scatter_kernel, dim3((NEDGES + 255) / 256), dim3(256), 0, stream,
                           edge_index, cursor, csr);
        hipLaunchKernelGGL(gather_kernel, dim3(1563), dim3(256), 0, stream,
                           tp, offsets, csr, node_attr, out);
    } else {
        // fallback: atomic scatter (round-2 path)
        float* summed = (float*)d_ws;
        float* counts = summed + (size_t)NNODES * 40;
        hipMemsetAsync(d_ws, 0, (size_t)(NNODES * 40 + NNODES) * sizeof(float), stream);
        hipLaunchKernelGGL((tp_mfma_kernel<0>), dim3(512), dim3(512), 0, stream,
                           node_attr, edge_index, edge_attr, edge_sh, w1, b1, w2, b2,
                           summed, counts, (float*)nullptr, (int*)nullptr);
        int fblk = (NNODES * 40 + 255) / 256;
        hipLaunchKernelGGL(finalize_kernel, dim3(fblk), dim3(256), 0, stream,
                           summed, counts, node_attr, out);
    }
}